// Round 7
// baseline (88.217 us; speedup 1.0000x reference)
//
#include <hip/hip_runtime.h>

#define RADIUS 5
#define KSIZE  11
#define TILEX  32                   // output px per block in x (2 per px-pair)
#define TILEY  16
#define HX     (TILEX + 2*RADIUS)   // 42
#define HY     (TILEY + 2*RADIUS)   // 26
#define HPITCH 21                   // half-columns per row (42/2), odd
#define H      256
#define W      256

// -0.5*log2(e)*sigma_inv, groups: ch0-1 (10.0), ch2-4 (0.02), ch5-7 (0.1)
#define COEF_A (-0.072134752f)
#define COEF_B (-36.06737602f)
#define COEF_C (-7.213475204f)

__device__ __forceinline__ float wcalc(const float4 a, const float4 g,
                                       const float4 cA, const float4 cB) {
    const float d0 = a.x - cA.x, d1 = a.y - cA.y;
    const float d2 = a.z - cA.z, d3 = a.w - cA.w;
    const float d4 = g.x - cB.x, d5 = g.y - cB.y;
    const float d6 = g.z - cB.z, d7 = g.w - cB.w;
    const float sA = d0 * d0 + d1 * d1;
    const float sB = d2 * d2 + d3 * d3 + d4 * d4;
    const float sC = d5 * d5 + d6 * d6 + d7 * d7;
    return __builtin_amdgcn_exp2f(COEF_A * sA + COEF_B * sB + COEF_C * sC);
}

// R7 = R6 kernel UNCHANGED, launched twice (idempotent) to measure one kernel
// execution as dur_R7 - dur_R6. Block (16,4,16): threadIdx.x = px-pair (lane
// bits 0-3, contiguous b128), threadIdx.y = dy-quarter (lane bits 4-5),
// threadIdx.z = px y (wave index).
__global__ __launch_bounds__(1024, 4) void jbf_kernel(
    const float* __restrict__ image,     // (B,3,H,W)
    const float* __restrict__ guidance,  // (B,8,H,W)
    float* __restrict__ out)             // (B,3,H,W)
{
    __shared__ float4 g0e[HY * HPITCH], g0o[HY * HPITCH];  // guidance ch0-3
    __shared__ float4 g1e[HY * HPITCH], g1o[HY * HPITCH];  // guidance ch4-7
    __shared__ float4 ime[HY * HPITCH], imo[HY * HPITCH];  // image ch0-2

    const int b       = blockIdx.z;
    const int tile_x0 = blockIdx.x * TILEX;
    const int tile_y0 = blockIdx.y * TILEY;
    const int txp     = threadIdx.x;        // px-pair index in x (lane bits 0-3)
    const int h       = threadIdx.y;        // dy-quarter 0..3 (lane bits 4-5)
    const int typ     = threadIdx.z;        // px y within tile (wave index)
    const int tid     = (typ * 4 + h) * 16 + txp;

    const float* gbase = guidance + (size_t)b * 8 * H * W;
    const float* ibase = image    + (size_t)b * 3 * H * W;

    for (int idx = tid; idx < HX * HY; idx += 1024) {
        const int ly = idx / HX;
        const int lx = idx - ly * HX;
        int gy = tile_y0 - RADIUS + ly;
        int gx = tile_x0 - RADIUS + lx;
        gy = (gy < 0) ? -gy : ((gy >= H) ? 2 * (H - 1) - gy : gy);
        gx = (gx < 0) ? -gx : ((gx >= W) ? 2 * (W - 1) - gx : gx);
        const int off = gy * W + gx;
        const int l   = ly * HPITCH + (lx >> 1);
        const float4 v0 = make_float4(gbase[0*H*W+off], gbase[1*H*W+off],
                                      gbase[2*H*W+off], gbase[3*H*W+off]);
        const float4 v1 = make_float4(gbase[4*H*W+off], gbase[5*H*W+off],
                                      gbase[6*H*W+off], gbase[7*H*W+off]);
        const float4 vi = make_float4(ibase[0*H*W+off], ibase[1*H*W+off],
                                      ibase[2*H*W+off], 0.f);
        if (lx & 1) { g0o[l] = v0; g1o[l] = v1; imo[l] = vi; }
        else        { g0e[l] = v0; g1e[l] = v1; ime[l] = vi; }
    }
    __syncthreads();

    const int crow = (typ + RADIUS) * HPITCH;
    const float4 c0A = g0o[crow + txp + 2], c0B = g1o[crow + txp + 2];
    const float4 c1A = g0e[crow + txp + 3], c1B = g1e[crow + txp + 3];

    float a00 = 0.f, a01 = 0.f, a02 = 0.f, sw0 = 0.f;
    float a10 = 0.f, a11 = 0.f, a12 = 0.f, sw1 = 0.f;

    #pragma unroll
    for (int i = 0; i < 3; ++i) {
        const int dy = 4 * i + h;
        if (dy < KSIZE) {
            const int rb = (typ + dy) * HPITCH + txp;
            #pragma unroll
            for (int k = 0; k <= 5; ++k) {
                const float4 Eg0 = g0e[rb + k], Eg1 = g1e[rb + k], Eim = ime[rb + k];
                const float4 Og0 = g0o[rb + k], Og1 = g1o[rb + k], Oim = imo[rb + k];

                {   // px0, dx=2k (even col)
                    const float w = wcalc(Eg0, Eg1, c0A, c0B);
                    sw0 += w; a00 += w * Eim.x; a01 += w * Eim.y; a02 += w * Eim.z;
                }
                if (k <= 4) {  // px0, dx=2k+1 (odd col)
                    const float w = wcalc(Og0, Og1, c0A, c0B);
                    sw0 += w; a00 += w * Oim.x; a01 += w * Oim.y; a02 += w * Oim.z;
                }
                {   // px1, dx=2k (odd col)
                    const float w = wcalc(Og0, Og1, c1A, c1B);
                    sw1 += w; a10 += w * Oim.x; a11 += w * Oim.y; a12 += w * Oim.z;
                }
                if (k >= 1) {  // px1, dx=2k-1 (even col)
                    const float w = wcalc(Eg0, Eg1, c1A, c1B);
                    sw1 += w; a10 += w * Eim.x; a11 += w * Eim.y; a12 += w * Eim.z;
                }
            }
        }
    }

    sw0 += __shfl_xor(sw0, 16);  sw0 += __shfl_xor(sw0, 32);
    a00 += __shfl_xor(a00, 16);  a00 += __shfl_xor(a00, 32);
    a01 += __shfl_xor(a01, 16);  a01 += __shfl_xor(a01, 32);
    a02 += __shfl_xor(a02, 16);  a02 += __shfl_xor(a02, 32);
    sw1 += __shfl_xor(sw1, 16);  sw1 += __shfl_xor(sw1, 32);
    a10 += __shfl_xor(a10, 16);  a10 += __shfl_xor(a10, 32);
    a11 += __shfl_xor(a11, 16);  a11 += __shfl_xor(a11, 32);
    a12 += __shfl_xor(a12, 16);  a12 += __shfl_xor(a12, 32);

    if (h == 0) {
        const float inv0 = 1.0f / sw0;
        const float inv1 = 1.0f / sw1;
        const size_t o = (size_t)b * 3 * H * W + (size_t)(tile_y0 + typ) * W
                       + (size_t)(tile_x0 + 2 * txp);
        float2* __restrict__ o2 = (float2*)(out + o);
        o2[0]           = make_float2(a00 * inv0, a10 * inv1);
        o2[(H*W) / 2]   = make_float2(a01 * inv0, a11 * inv1);
        o2[(2*H*W) / 2] = make_float2(a02 * inv0, a12 * inv1);
    }
}

extern "C" void kernel_launch(void* const* d_in, const int* in_sizes, int n_in,
                              void* d_out, int out_size, void* d_ws, size_t ws_size,
                              hipStream_t stream) {
    const float* image    = (const float*)d_in[0];
    const float* guidance = (const float*)d_in[1];
    float* out            = (float*)d_out;

    const int B = in_sizes[0] / (3 * H * W);   // = 2
    dim3 grid(W / TILEX, H / TILEY, B);        // 8 x 16 x 2 = 256 blocks
    dim3 block(16, 4, 16);                     // 1024 threads = 16 waves

    // PROBE: launch the identical kernel twice (idempotent — reads only
    // pristine inputs, rewrites the same output). dur_R7 - dur_R6 = one
    // kernel execution, cleanly separating kernel time from harness
    // restore/poison overhead that shares the timed stream.
    hipLaunchKernelGGL(jbf_kernel, grid, block, 0, stream, image, guidance, out);
    hipLaunchKernelGGL(jbf_kernel, grid, block, 0, stream, image, guidance, out);
}

// Round 8
// 71.616 us; speedup vs baseline: 1.2318x; 1.2318x over previous
//
#include <hip/hip_runtime.h>

#define RADIUS 5
#define TILEX  32                   // output px per block in x
#define TILEY  16                   // output px per block in y
#define HX     (TILEX + 2*RADIUS)   // 42
#define HY     (TILEY + 2*RADIUS)   // 26
#define HPITCH 21                   // half-columns per row (42/2), odd
#define H      256
#define W      256

// exp2-folded Mahalanobis coefficients kappa = -0.5*log2(e)*sigma_inv:
// ch0-1 (sigma 10.0), ch2-4 (0.02), ch5-7 (0.1)
#define KA (-0.072134752f)
#define KB (-36.06737602f)
#define KC (-7.213475204f)

struct Center { float4 hA, hB; float phic; };

// Quadratic expansion: sum k_i (gp_i - gc_i)^2 = phi(p) + phi(c) + sum h_i*gp_i
// with h_i = -2*k_i*gc_i, phi = sum k_i g_i^2 (staged in image .w).
__device__ __forceinline__ void accum(const float4 A, const float4 G, const float4 P,
                                      const Center& C, const float gate,
                                      float& sw, float& ax, float& ay, float& az) {
    const float t = P.w + C.phic
                  + C.hA.x*A.x + C.hA.y*A.y + C.hA.z*A.z + C.hA.w*A.w
                  + C.hB.x*G.x + C.hB.y*G.y + C.hB.z*G.z + C.hB.w*G.w;
    const float w = gate * __builtin_amdgcn_exp2f(t);
    sw += w; ax += w * P.x; ay += w * P.y; az += w * P.z;
}

// block (16,4,8): threadIdx.x = px-pair x (lane bits 0-3 -> contiguous b128),
// threadIdx.y = row-quarter h (lane bits 4-5 -> shfl_xor(16/32) combine),
// threadIdx.z = y-quad index (wave id). Each thread: 2x2 output px.
// 12 halo rows per y-quad split exactly 3/3/3/3 across h.
__global__ __launch_bounds__(512, 2) void jbf_kernel(
    const float* __restrict__ image,     // (B,3,H,W)
    const float* __restrict__ guidance,  // (B,8,H,W)
    float* __restrict__ out)             // (B,3,H,W)
{
    __shared__ float4 g0e[HY * HPITCH], g0o[HY * HPITCH];  // guidance ch0-3
    __shared__ float4 g1e[HY * HPITCH], g1o[HY * HPITCH];  // guidance ch4-7
    __shared__ float4 ime[HY * HPITCH], imo[HY * HPITCH];  // image ch0-2 + phi

    const int b       = blockIdx.z;
    const int tile_x0 = blockIdx.x * TILEX;
    const int tile_y0 = blockIdx.y * TILEY;
    const int txp     = threadIdx.x;        // 0..15
    const int h       = threadIdx.y;        // 0..3
    const int typ     = threadIdx.z;        // 0..7
    const int tid     = (typ * 4 + h) * 16 + txp;

    const float* gbase = guidance + (size_t)b * 8 * H * W;
    const float* ibase = image    + (size_t)b * 3 * H * W;

    // ---- stage 42x26 halo (reflect) into even/odd interleaved LDS ----
    for (int idx = tid; idx < HX * HY; idx += 512) {
        const int ly = idx / HX;
        const int lx = idx - ly * HX;
        int gy = tile_y0 - RADIUS + ly;
        int gx = tile_x0 - RADIUS + lx;
        gy = (gy < 0) ? -gy : ((gy >= H) ? 2 * (H - 1) - gy : gy);
        gx = (gx < 0) ? -gx : ((gx >= W) ? 2 * (W - 1) - gx : gx);
        const int off = gy * W + gx;
        const int l   = ly * HPITCH + (lx >> 1);
        const float4 v0 = make_float4(gbase[0*H*W+off], gbase[1*H*W+off],
                                      gbase[2*H*W+off], gbase[3*H*W+off]);
        const float4 v1 = make_float4(gbase[4*H*W+off], gbase[5*H*W+off],
                                      gbase[6*H*W+off], gbase[7*H*W+off]);
        const float phi = KA * (v0.x*v0.x + v0.y*v0.y)
                        + KB * (v0.z*v0.z + v0.w*v0.w + v1.x*v1.x)
                        + KC * (v1.y*v1.y + v1.z*v1.z + v1.w*v1.w);
        const float4 vi = make_float4(ibase[0*H*W+off], ibase[1*H*W+off],
                                      ibase[2*H*W+off], phi);
        if (lx & 1) { g0o[l] = v0; g1o[l] = v1; imo[l] = vi; }
        else        { g0e[l] = v0; g1e[l] = v1; ime[l] = vi; }
    }
    __syncthreads();

    // centers: x0 = halo col 2txp+5 (odd, idx txp+2), x1 = 2txp+6 (even, txp+3)
    //          y0 = halo row 2typ+5, y1 = 2typ+6
    Center c[2][2];
    #pragma unroll
    for (int cy = 0; cy < 2; ++cy) {
        const int row = (2 * typ + 5 + cy) * HPITCH;
        #pragma unroll
        for (int cx = 0; cx < 2; ++cx) {
            const int ci = row + txp + 2 + cx;
            const float4 gA = cx ? g0e[ci] : g0o[ci];
            const float4 gB = cx ? g1e[ci] : g1o[ci];
            const float4 pv = cx ? ime[ci] : imo[ci];
            c[cx][cy].hA = make_float4(-2.f*KA*gA.x, -2.f*KA*gA.y,
                                       -2.f*KB*gA.z, -2.f*KB*gA.w);
            c[cx][cy].hB = make_float4(-2.f*KB*gB.x, -2.f*KC*gB.y,
                                       -2.f*KC*gB.z, -2.f*KC*gB.w);
            c[cx][cy].phic = pv.w;
        }
    }

    float s[2][2]  = {{0.f,0.f},{0.f,0.f}};
    float ax[2][2] = {{0.f,0.f},{0.f,0.f}};
    float ay[2][2] = {{0.f,0.f},{0.f,0.f}};
    float az[2][2] = {{0.f,0.f},{0.f,0.f}};

    // quarter h handles halo rows r = h, h+4, h+8 of the quad's 12-row union.
    // Row r serves y0 iff r<=10, serves y1 iff r>=1 (gated via 0/1 multiply).
    #pragma unroll
    for (int i = 0; i < 3; ++i) {
        const int r  = 4 * i + h;
        const int rb = (2 * typ + r) * HPITCH + txp;
        const float fy0 = (r <= 10) ? 1.0f : 0.0f;
        const float fy1 = (r >= 1)  ? 1.0f : 0.0f;
        #pragma unroll
        for (int k = 0; k <= 5; ++k) {
            {   // EVEN columns: serve x0 (all k: dx=2k-5), x1 (k>=1: dx=2k-6)
                const float4 A = g0e[rb + k], G = g1e[rb + k], P = ime[rb + k];
                accum(A, G, P, c[0][0], fy0, s[0][0], ax[0][0], ay[0][0], az[0][0]);
                accum(A, G, P, c[0][1], fy1, s[0][1], ax[0][1], ay[0][1], az[0][1]);
                if (k >= 1) {
                    accum(A, G, P, c[1][0], fy0, s[1][0], ax[1][0], ay[1][0], az[1][0]);
                    accum(A, G, P, c[1][1], fy1, s[1][1], ax[1][1], ay[1][1], az[1][1]);
                }
            }
            {   // ODD columns: serve x0 (k<=4: dx=2k-4), x1 (all k: dx=2k-5)
                const float4 A = g0o[rb + k], G = g1o[rb + k], P = imo[rb + k];
                if (k <= 4) {
                    accum(A, G, P, c[0][0], fy0, s[0][0], ax[0][0], ay[0][0], az[0][0]);
                    accum(A, G, P, c[0][1], fy1, s[0][1], ax[0][1], ay[0][1], az[0][1]);
                }
                accum(A, G, P, c[1][0], fy0, s[1][0], ax[1][0], ay[1][0], az[1][0]);
                accum(A, G, P, c[1][1], fy1, s[1][1], ax[1][1], ay[1][1], az[1][1]);
            }
        }
    }

    // combine row-quarter partials: butterfly over lane bits 4-5 (h)
    #pragma unroll
    for (int cx = 0; cx < 2; ++cx)
        #pragma unroll
        for (int cy = 0; cy < 2; ++cy) {
            s[cx][cy]  += __shfl_xor(s[cx][cy], 16);  s[cx][cy]  += __shfl_xor(s[cx][cy], 32);
            ax[cx][cy] += __shfl_xor(ax[cx][cy], 16); ax[cx][cy] += __shfl_xor(ax[cx][cy], 32);
            ay[cx][cy] += __shfl_xor(ay[cx][cy], 16); ay[cx][cy] += __shfl_xor(ay[cx][cy], 32);
            az[cx][cy] += __shfl_xor(az[cx][cy], 16); az[cx][cy] += __shfl_xor(az[cx][cy], 32);
        }

    if (h == 0) {
        // sum_w >= ~1 (center weight ~ 1); reference clip(1e-10) is a no-op
        const size_t base = (size_t)b * 3 * H * W
                          + (size_t)(tile_y0 + 2 * typ) * W + (tile_x0 + 2 * txp);
        #pragma unroll
        for (int cy = 0; cy < 2; ++cy) {
            const float i0 = 1.0f / s[0][cy];
            const float i1 = 1.0f / s[1][cy];
            float2* __restrict__ o2 = (float2*)(out + base + (size_t)cy * W);
            o2[0]           = make_float2(ax[0][cy] * i0, ax[1][cy] * i1);
            o2[(H*W) / 2]   = make_float2(ay[0][cy] * i0, ay[1][cy] * i1);
            o2[(2*H*W) / 2] = make_float2(az[0][cy] * i0, az[1][cy] * i1);
        }
    }
}

extern "C" void kernel_launch(void* const* d_in, const int* in_sizes, int n_in,
                              void* d_out, int out_size, void* d_ws, size_t ws_size,
                              hipStream_t stream) {
    const float* image    = (const float*)d_in[0];
    const float* guidance = (const float*)d_in[1];
    float* out            = (float*)d_out;

    const int B = in_sizes[0] / (3 * H * W);   // = 2
    dim3 grid(W / TILEX, H / TILEY, B);        // 8 x 16 x 2 = 256 blocks
    dim3 block(16, 4, 8);                      // 512 threads = 8 waves
    hipLaunchKernelGGL(jbf_kernel, grid, block, 0, stream, image, guidance, out);
}